// Round 2
// baseline (2303.330 us; speedup 1.0000x reference)
//
#include <hip/hip_runtime.h>

#define TS 0.01f
constexpr int NX = 32, NU = 16, NF = 512;
constexpr int SEQ = 2048;
constexpr int CH = 32;          // steps per u-chunk / output-flush chunk
constexpr int NT = 512;         // threads per block
constexpr int RPB = 2;          // batch rows per block

__device__ __forceinline__ float fast_tanh(float y) {
    y = fminf(15.f, fmaxf(-15.f, y));
    float e = __expf(2.f * y);                        // e^{2y}, finite after clamp
    return (e - 1.f) * __builtin_amdgcn_rcpf(e + 1.f);
}

__global__ __launch_bounds__(NT, 2) void fes_kernel(
    const float* __restrict__ x0, const float* __restrict__ ug,
    const float* __restrict__ W1, const float* __restrict__ b1,
    const float* __restrict__ W2, const float* __restrict__ b2,
    float* __restrict__ out)
{
    __shared__ float4 xs4[RPB][NX / 4];           // current state, broadcast
    __shared__ float4 hs4[RPB][NF / 4];           // activations
    __shared__ float4 us4[RPB][CH][NU / 4];       // u chunk (2 KB... 2*32*4*16B = 4 KB)
    __shared__ float4 xo4[RPB * CH * NX / 4];     // output staging (512 float4 = 8 KB)

    const int tid  = threadIdx.x;
    const int row0 = blockIdx.x * RPB;

    // ---- persistent registers --------------------------------------------
    // W1 column for this thread's feature (f = tid): 48 VGPRs
    float w1c[48];
#pragma unroll
    for (int k = 0; k < 48; ++k) w1c[k] = W1[k * NF + tid];
    const float b1r = b1[tid];

    // GEMM2 mapping: group g = tid/8 -> output (r2 = g/32, j = g%32); lane l = tid%8
    const int g  = tid >> 3, l = tid & 7;
    const int r2 = g >> 5,  j = g & 31;
    // W2 k-slice for this lane: k = 4*l + 32*i + c  (i<16, c<4) -> 64 VGPRs
    float w2r[64];
#pragma unroll
    for (int i = 0; i < 16; ++i)
#pragma unroll
        for (int c = 0; c < 4; ++c)
            w2r[i * 4 + c] = W2[(4 * l + 32 * i + c) * NX + j];
    const float b2r = b2[j];
    float xreg = x0[(row0 + r2) * NX + j];   // this group's own state element

    // init shared state (RPB*NX = 64 floats)
    if (tid < RPB * NX) ((float*)xs4)[tid] = x0[row0 * NX + tid];
    __syncthreads();

    for (int t0 = 0; t0 < SEQ; t0 += CH) {
        // ---- phase 0: flush previous chunk's outputs, load u chunk -------
        // xo4: 512 float4 = 2 rows x 256 float4; float4 index rem = tc*8 + jj
        if (t0 > 0) {
            const int tp  = t0 - CH;
            const int r   = tid >> 8;          // 0..1
            const int rem = tid & 255;         // 256 float4 per row-chunk
            const int tc  = rem >> 3, jj = rem & 7;
            float4 v = xo4[r * (CH * NX / 4) + rem];
            *(float4*)&out[(size_t)(row0 + r) * SEQ * NX + (size_t)(tp + tc) * NX + jj * 4] = v;
        }
        // u chunk: 2 rows x 512 floats (contiguous per row) = 256 float4
        if (tid < 256) {
            const int r   = tid >> 7;          // 0..1
            const int rem = tid & 127;         // float4 index within row-chunk
            ((float4*)us4)[r * (CH * NU / 4) + rem] =
                *(const float4*)&ug[(size_t)(row0 + r) * SEQ * NU + (size_t)t0 * NU + rem * 4];
        }
        __syncthreads();

        for (int tc = 0; tc < CH; ++tc) {
            // ---- phase 1: h[r][tid] = tanh(W1^T [x;u] + b1) --------------
            float a0a = 0.f, a0b = 0.f, a1a = 0.f, a1b = 0.f;
#pragma unroll
            for (int kk = 0; kk < 8; ++kk) {
                const float4 xv0 = xs4[0][kk];
                const float4 xv1 = xs4[1][kk];
                const float wa = w1c[4 * kk], wb = w1c[4 * kk + 1];
                const float wc = w1c[4 * kk + 2], wd = w1c[4 * kk + 3];
                a0a = fmaf(wa, xv0.x, a0a); a0b = fmaf(wb, xv0.y, a0b);
                a0a = fmaf(wc, xv0.z, a0a); a0b = fmaf(wd, xv0.w, a0b);
                a1a = fmaf(wa, xv1.x, a1a); a1b = fmaf(wb, xv1.y, a1b);
                a1a = fmaf(wc, xv1.z, a1a); a1b = fmaf(wd, xv1.w, a1b);
            }
#pragma unroll
            for (int kk = 0; kk < 4; ++kk) {
                const float4 uv0 = us4[0][tc][kk];
                const float4 uv1 = us4[1][tc][kk];
                const float wa = w1c[32 + 4 * kk], wb = w1c[33 + 4 * kk];
                const float wc = w1c[34 + 4 * kk], wd = w1c[35 + 4 * kk];
                a0a = fmaf(wa, uv0.x, a0a); a0b = fmaf(wb, uv0.y, a0b);
                a0a = fmaf(wc, uv0.z, a0a); a0b = fmaf(wd, uv0.w, a0b);
                a1a = fmaf(wa, uv1.x, a1a); a1b = fmaf(wb, uv1.y, a1b);
                a1a = fmaf(wc, uv1.z, a1a); a1b = fmaf(wd, uv1.w, a1b);
            }
            const float h0 = fast_tanh(a0a + a0b + b1r);
            const float h1 = fast_tanh(a1a + a1b + b1r);
            ((float*)hs4)[tid]      = h0;
            ((float*)hs4)[NF + tid] = h1;
            __syncthreads();

            // ---- phase 2: dx[r2][j] = W2^T h, update state ---------------
            float s0 = 0.f, s1 = 0.f, s2 = 0.f, s3 = 0.f;
#pragma unroll
            for (int i = 0; i < 16; ++i) {
                const float4 hv = hs4[r2][l + 8 * i];   // 8 lines/wave, all 32 banks
                s0 = fmaf(hv.x, w2r[4 * i],     s0);
                s1 = fmaf(hv.y, w2r[4 * i + 1], s1);
                s2 = fmaf(hv.z, w2r[4 * i + 2], s2);
                s3 = fmaf(hv.w, w2r[4 * i + 3], s3);
            }
            float s = (s0 + s1) + (s2 + s3);
            s += __shfl_xor(s, 1);
            s += __shfl_xor(s, 2);
            s += __shfl_xor(s, 4);
            const float xn = fmaf(TS, s + b2r, xreg);
            xreg = xn;
            if (l == 0) {
                ((float*)xs4)[r2 * NX + j]                  = xn;
                ((float*)xo4)[r2 * (CH * NX) + tc * NX + j] = xn;
            }
            __syncthreads();
        }
    }

    // ---- final flush ------------------------------------------------------
    {
        const int tp  = SEQ - CH;
        const int r   = tid >> 8;
        const int rem = tid & 255;
        const int tc  = rem >> 3, jj = rem & 7;
        float4 v = xo4[r * (CH * NX / 4) + rem];
        *(float4*)&out[(size_t)(row0 + r) * SEQ * NX + (size_t)(tp + tc) * NX + jj * 4] = v;
    }
}

extern "C" void kernel_launch(void* const* d_in, const int* in_sizes, int n_in,
                              void* d_out, int out_size, void* d_ws, size_t ws_size,
                              hipStream_t stream) {
    const float* x0 = (const float*)d_in[0];
    const float* ug = (const float*)d_in[1];
    const float* W1 = (const float*)d_in[2];
    const float* b1 = (const float*)d_in[3];
    const float* W2 = (const float*)d_in[4];
    const float* b2 = (const float*)d_in[5];
    float* out = (float*)d_out;

    dim3 grid(512 / RPB);   // 256 blocks, 2 rows each
    dim3 block(NT);
    fes_kernel<<<grid, block, 0, stream>>>(x0, ug, W1, b1, W2, b2, out);
}